// Round 1
// baseline (100.178 us; speedup 1.0000x reference)
//
#include <hip/hip_runtime.h>
#include <math.h>

// B=1024, D=128, H=128
#define Bn 1024
#define Dn 128
#define Hn 128

// ---------------------------------------------------------------------------
// Kernel A: per-column sort-based computation of dmean[i][d] =
//   mean_j |x[i][d] - x[j][d]|
// For a sorted column v_0<=...<=v_{B-1}, with exclusive prefix P(k) and total
// T:  sum_j |v_k - v_j| = (2k - B)*v_k - 2*P(k) + T.
// One block per column d. 1024 threads, element at sorted position t lives in
// thread t. Bitonic network: 55 steps; j<64 steps are in-wave shfl_xor (no
// barrier), j>=64 steps (10 of them) go through LDS. Keys are packed
// (sortable-float << 32) | original-index, so ties are strict and the original
// row index rides along for the final scatter.
// ---------------------------------------------------------------------------
__global__ __launch_bounds__(1024) void col_sort_dmean(
    const float* __restrict__ x, float* __restrict__ dmean) {
  const int d = blockIdx.x;
  const int t = threadIdx.x;

  __shared__ unsigned long long kvs[Bn];  // 8 KB
  __shared__ float wsum[16];

  // Column load (uncoalesced 4B, one per thread; 16 waves hide the latency).
  const float v0 = x[(size_t)t * Dn + d];
  const unsigned int u = __float_as_uint(v0);
  // Monotonic float->uint map: positives get top bit set, negatives bit-flip.
  const unsigned int key = u ^ ((u >> 31) ? 0xFFFFFFFFu : 0x80000000u);
  unsigned long long kv = ((unsigned long long)key << 32) | (unsigned int)t;

  // Bitonic sort.
#pragma unroll
  for (int k = 2; k <= Bn; k <<= 1) {
#pragma unroll
    for (int j = k >> 1; j > 0; j >>= 1) {
      unsigned long long other;
      if (j >= 64) {
        kvs[t] = kv;
        __syncthreads();
        other = kvs[t ^ j];
        __syncthreads();  // protect next step's write (WAR)
      } else {
        other = __shfl_xor(kv, j, 64);
      }
      const bool up = ((t & k) == 0);       // ascending sub-block
      const bool lowHalf = ((t & j) == 0);  // lower element of the pair
      const bool keepMin = (up == lowHalf);
      const bool otherSmaller = (other < kv);
      if (keepMin == otherSmaller) kv = other;  // ties impossible (idx unique)
    }
  }

  // Unpack sorted value + original row.
  const unsigned int skey = (unsigned int)(kv >> 32);
  const unsigned int orig = (unsigned int)(kv & 0xFFFFFFFFu);
  const unsigned int ub =
      (skey & 0x80000000u) ? (skey ^ 0x80000000u) : ~skey;
  const float sv = __uint_as_float(ub);

  // Exclusive prefix sum across the 1024 sorted values.
  const int lane = t & 63;
  const int wv = t >> 6;
  float ps = sv;  // inclusive within wave
#pragma unroll
  for (int off = 1; off < 64; off <<= 1) {
    const float n = __shfl_up(ps, off, 64);
    if (lane >= off) ps += n;
  }
  if (lane == 63) wsum[wv] = ps;
  __syncthreads();
  float woff = 0.f, tot = 0.f;
#pragma unroll
  for (int w = 0; w < 16; ++w) {
    const float s = wsum[w];
    tot += s;
    if (w < wv) woff += s;
  }
  const float pexcl = (ps - sv) + woff;

  const float res =
      ((float)(2 * t - Bn) * sv + tot - 2.0f * pexcl) * (1.0f / (float)Bn);
  dmean[(size_t)orig * Dn + d] = res;  // scatter to original row
}

// ---------------------------------------------------------------------------
// Kernel B: tau / matvec chain / LayerNorm tail (verified structure from the
// previous fused kernel, with dmean read from global). 256 blocks x 256
// threads, 4 rows per block.
// ---------------------------------------------------------------------------
__global__ __launch_bounds__(256) void fused_tail(
    const float* __restrict__ x, const float* __restrict__ dmean,
    const float* __restrict__ Wd, const float* __restrict__ bd,
    const float* __restrict__ Wt, const float* __restrict__ bt,
    const float* __restrict__ Wa, const float* __restrict__ ba,
    const float* __restrict__ Wr, const float* __restrict__ br,
    const float* __restrict__ gamma, const float* __restrict__ beta,
    float* __restrict__ out) {
  const int t = threadIdx.x;
  const int i0 = blockIdx.x << 2;

  __shared__ float xs[4][Dn];
  __shared__ float dms[4][Dn];
  __shared__ float ms[4][Hn];
  __shared__ float ys[4][Hn];
  __shared__ float wt_s[Dn];
  __shared__ float tau_s[4];  // 1/tau

  // ---- Stage x rows, dmean rows, Wt ----
  {
    const int r = t >> 6, p2 = (t & 63) << 1;
    *(float2*)&xs[r][p2] = *(const float2*)(x + (size_t)(i0 + r) * Dn + p2);
    *(float2*)&dms[r][p2] =
        *(const float2*)(dmean + (size_t)(i0 + r) * Dn + p2);
    if (t < Dn) wt_s[t] = Wt[t];
  }
  __syncthreads();

  // ---- tau (one wave per row) ----
  {
    const int r = t >> 6, p = t & 63;
    float partial = xs[r][p] * wt_s[p] + xs[r][p + 64] * wt_s[p + 64];
#pragma unroll
    for (int off = 32; off; off >>= 1) partial += __shfl_xor(partial, off, 64);
    if (p == 0) {
      const float z = partial + bt[0];
      const float sp = fmaxf(z, 0.f) + log1pf(expf(-fabsf(z)));  // softplus
      tau_s[r] = 1.0f / (fmaxf(sp, 0.01f) + 1.0f);
    }
  }
  __syncthreads();

  // ---- m = (Wd . dm + bd) / tau ----
  {
    const int h = t & 127;
    const int g4 = t >> 7;
    const int r0 = 2 * g4, r1 = 2 * g4 + 1;
    float m0 = bd[h], m1 = m0;
    const float4* w = (const float4*)(Wd + (size_t)h * Dn);
#pragma unroll 4
    for (int k4 = 0; k4 < Dn / 4; ++k4) {
      const float4 wv = w[k4];
      const int k = k4 * 4;
      m0 += wv.x * dms[r0][k] + wv.y * dms[r0][k + 1] + wv.z * dms[r0][k + 2] +
            wv.w * dms[r0][k + 3];
      m1 += wv.x * dms[r1][k] + wv.y * dms[r1][k + 1] + wv.z * dms[r1][k + 2] +
            wv.w * dms[r1][k + 3];
    }
    ms[r0][h] = m0 * tau_s[r0];
    ms[r1][h] = m1 * tau_s[r1];
  }
  __syncthreads();

  // ---- y = relu(Wa . m + ba) + Wr . x + br ----
  {
    const int h = t & 127;
    const int g4 = t >> 7;
    const int r0 = 2 * g4, r1 = 2 * g4 + 1;
    float q0 = ba[h], q1 = q0, c0 = br[h], c1 = c0;
    const float4* wa = (const float4*)(Wa + (size_t)h * Dn);
    const float4* wr = (const float4*)(Wr + (size_t)h * Dn);
#pragma unroll 4
    for (int k4 = 0; k4 < Dn / 4; ++k4) {
      const float4 av = wa[k4];
      const float4 rv = wr[k4];
      const int k = k4 * 4;
      q0 += av.x * ms[r0][k] + av.y * ms[r0][k + 1] + av.z * ms[r0][k + 2] +
            av.w * ms[r0][k + 3];
      q1 += av.x * ms[r1][k] + av.y * ms[r1][k + 1] + av.z * ms[r1][k + 2] +
            av.w * ms[r1][k + 3];
      c0 += rv.x * xs[r0][k] + rv.y * xs[r0][k + 1] + rv.z * xs[r0][k + 2] +
            rv.w * xs[r0][k + 3];
      c1 += rv.x * xs[r1][k] + rv.y * xs[r1][k + 1] + rv.z * xs[r1][k + 2] +
            rv.w * xs[r1][k + 3];
    }
    ys[r0][h] = fmaxf(q0, 0.f) + c0;
    ys[r1][h] = fmaxf(q1, 0.f) + c1;
  }
  __syncthreads();

  // ---- LayerNorm (one wave per row) ----
  {
    const int r = t >> 6, p = t & 63;
    const float v0 = ys[r][p], v1 = ys[r][p + 64];
    float s = v0 + v1;
    float q = v0 * v0 + v1 * v1;
#pragma unroll
    for (int off = 32; off; off >>= 1) {
      s += __shfl_xor(s, off, 64);
      q += __shfl_xor(q, off, 64);
    }
    const float mu = s * (1.0f / 128.0f);
    const float var = q * (1.0f / 128.0f) - mu * mu;
    const float rs = rsqrtf(var + 1e-5f);
    float* o = out + (size_t)(i0 + r) * Hn;
    o[p] = (v0 - mu) * rs * gamma[p] + beta[p];
    o[p + 64] = (v1 - mu) * rs * gamma[p + 64] + beta[p + 64];
  }
}

extern "C" void kernel_launch(void* const* d_in, const int* in_sizes, int n_in,
                              void* d_out, int out_size, void* d_ws,
                              size_t ws_size, hipStream_t stream) {
  const float* x = (const float*)d_in[0];
  const float* Wd = (const float*)d_in[1];
  const float* bd = (const float*)d_in[2];
  const float* Wt = (const float*)d_in[3];
  const float* bt = (const float*)d_in[4];
  const float* Wa = (const float*)d_in[5];
  const float* ba = (const float*)d_in[6];
  const float* Wr = (const float*)d_in[7];
  const float* br = (const float*)d_in[8];
  const float* gamma = (const float*)d_in[9];
  const float* beta = (const float*)d_in[10];
  float* out = (float*)d_out;
  float* dmean = (float*)d_ws;  // B*D*4 = 512 KB scratch

  col_sort_dmean<<<Dn, Bn, 0, stream>>>(x, dmean);
  fused_tail<<<Bn / 4, 256, 0, stream>>>(x, dmean, Wd, bd, Wt, bt, Wa, ba, Wr,
                                         br, gamma, beta, out);
  (void)in_sizes; (void)n_in; (void)out_size; (void)ws_size;
}

// Round 2
// 98.854 us; speedup vs baseline: 1.0134x; 1.0134x over previous
//
#include <hip/hip_runtime.h>
#include <math.h>

// B=1024, D=128, H=128
#define Bn 1024
#define Dn 128
#define Hn 128

// ---------------------------------------------------------------------------
// Kernel A: per-column sort-based dmean[i][d] = mean_j |x[i][d] - x[j][d]|.
// For sorted column v_0<=...<=v_{B-1}, exclusive prefix P(k), total T:
//   sum_j |v - v_j| = (2*k0 - B)*v - 2*P(k0) + T,  k0 = #{j : v_j < v}
// (exact under ties with lower_bound rank, since tied elements contribute 0).
//
// One block per column d (128 blocks x 1024 threads). Bitonic sort of 32-bit
// monotonic keys ONLY (no index payload): 45 in-wave steps = 1 ds_bpermute
// each; 10 cross-wave steps via double-buffered LDS = 1 barrier each (write
// buf, sync, read buf, toggle — WAR-safe because the other buffer is written
// next and every read precedes the next barrier in program order).
// Rank recovered afterward by a 10-step lower_bound binary search in LDS;
// each thread keeps its original value, so the dmean store needs no index.
// ---------------------------------------------------------------------------
__global__ __launch_bounds__(1024) void col_sort_dmean(
    const float* __restrict__ x, float* __restrict__ dmean) {
  const int d = blockIdx.x;
  const int t = threadIdx.x;

  __shared__ unsigned int kbuf[2][Bn];  // 8 KB exchange / sorted keys
  __shared__ float pref_s[Bn];          // 4 KB exclusive prefix of sorted vals
  __shared__ float wsum[16];

  // Column load (stride-512B gather; x is L2-resident, 16 waves hide latency).
  const float v0 = x[(size_t)t * Dn + d];
  const unsigned int u = __float_as_uint(v0);
  // Monotonic float->uint map (same as verified v2).
  const unsigned int mykey = u ^ ((u >> 31) ? 0xFFFFFFFFu : 0x80000000u);
  unsigned int key = mykey;

  // ---- Bitonic sort of keys ----
  int buf = 0;
#pragma unroll
  for (int k = 2; k <= Bn; k <<= 1) {
#pragma unroll
    for (int j = k >> 1; j >= 64; j >>= 1) {  // cross-wave: LDS exchange
      kbuf[buf][t] = key;
      __syncthreads();
      const unsigned int other = kbuf[buf][t ^ j];
      buf ^= 1;
      const bool keepMin = (((t & k) == 0) == ((t & j) == 0));
      if ((other < key) == keepMin) key = other;
    }
    const int j0 = ((k >> 1) < 32) ? (k >> 1) : 32;
#pragma unroll
    for (int j = j0; j > 0; j >>= 1) {  // in-wave: single-bpermute shuffle
      const unsigned int other = (unsigned int)__shfl_xor((int)key, j, 64);
      const bool keepMin = (((t & k) == 0) == ((t & j) == 0));
      if ((other < key) == keepMin) key = other;
    }
  }

  // Thread t now holds the sorted key at position t. Publish sorted keys.
  // (Safe without a barrier: kbuf[0] was last read before the final LDS
  // step's barrier, which all waves have passed.)
  kbuf[0][t] = key;

  // Unpack sorted value for the prefix scan.
  const unsigned int ub = (key & 0x80000000u) ? (key ^ 0x80000000u) : ~key;
  const float sv = __uint_as_float(ub);

  // ---- Exclusive prefix sum over sorted values ----
  const int lane = t & 63;
  const int wv = t >> 6;
  float ps = sv;  // inclusive within wave
#pragma unroll
  for (int off = 1; off < 64; off <<= 1) {
    const float n = __shfl_up(ps, off, 64);
    if (lane >= off) ps += n;
  }
  if (lane == 63) wsum[wv] = ps;
  __syncthreads();  // covers wsum writes AND sorted-key publish
  float woff = 0.f, tot = 0.f;
#pragma unroll
  for (int w = 0; w < 16; ++w) {
    const float s = wsum[w];
    tot += s;
    if (w < wv) woff += s;
  }
  pref_s[t] = (ps - sv) + woff;  // exclusive prefix at sorted position t
  __syncthreads();

  // ---- Rank via lower_bound binary search (10 dependent LDS reads) ----
  unsigned int pos = 0;
#pragma unroll
  for (int s = 512; s > 0; s >>= 1) {
    if (kbuf[0][pos + s - 1] < mykey) pos += s;
  }
  const float P = pref_s[pos];

  const float res =
      ((float)(2 * (int)pos - Bn) * v0 + tot - 2.0f * P) * (1.0f / (float)Bn);
  dmean[(size_t)t * Dn + d] = res;  // row-major scatter store (fire-and-forget)
}

// ---------------------------------------------------------------------------
// Kernel B: tau / matvec chain / LayerNorm tail (verified, unchanged from v2).
// 256 blocks x 256 threads, 4 rows per block; dmean read coalesced.
// ---------------------------------------------------------------------------
__global__ __launch_bounds__(256) void fused_tail(
    const float* __restrict__ x, const float* __restrict__ dmean,
    const float* __restrict__ Wd, const float* __restrict__ bd,
    const float* __restrict__ Wt, const float* __restrict__ bt,
    const float* __restrict__ Wa, const float* __restrict__ ba,
    const float* __restrict__ Wr, const float* __restrict__ br,
    const float* __restrict__ gamma, const float* __restrict__ beta,
    float* __restrict__ out) {
  const int t = threadIdx.x;
  const int i0 = blockIdx.x << 2;

  __shared__ float xs[4][Dn];
  __shared__ float dms[4][Dn];
  __shared__ float ms[4][Hn];
  __shared__ float ys[4][Hn];
  __shared__ float wt_s[Dn];
  __shared__ float tau_s[4];  // 1/tau

  // ---- Stage x rows, dmean rows, Wt ----
  {
    const int r = t >> 6, p2 = (t & 63) << 1;
    *(float2*)&xs[r][p2] = *(const float2*)(x + (size_t)(i0 + r) * Dn + p2);
    *(float2*)&dms[r][p2] =
        *(const float2*)(dmean + (size_t)(i0 + r) * Dn + p2);
    if (t < Dn) wt_s[t] = Wt[t];
  }
  __syncthreads();

  // ---- tau (one wave per row) ----
  {
    const int r = t >> 6, p = t & 63;
    float partial = xs[r][p] * wt_s[p] + xs[r][p + 64] * wt_s[p + 64];
#pragma unroll
    for (int off = 32; off; off >>= 1) partial += __shfl_xor(partial, off, 64);
    if (p == 0) {
      const float z = partial + bt[0];
      const float sp = fmaxf(z, 0.f) + log1pf(expf(-fabsf(z)));  // softplus
      tau_s[r] = 1.0f / (fmaxf(sp, 0.01f) + 1.0f);
    }
  }
  __syncthreads();

  // ---- m = (Wd . dm + bd) / tau ----
  {
    const int h = t & 127;
    const int g4 = t >> 7;
    const int r0 = 2 * g4, r1 = 2 * g4 + 1;
    float m0 = bd[h], m1 = m0;
    const float4* w = (const float4*)(Wd + (size_t)h * Dn);
#pragma unroll 4
    for (int k4 = 0; k4 < Dn / 4; ++k4) {
      const float4 wv = w[k4];
      const int k = k4 * 4;
      m0 += wv.x * dms[r0][k] + wv.y * dms[r0][k + 1] + wv.z * dms[r0][k + 2] +
            wv.w * dms[r0][k + 3];
      m1 += wv.x * dms[r1][k] + wv.y * dms[r1][k + 1] + wv.z * dms[r1][k + 2] +
            wv.w * dms[r1][k + 3];
    }
    ms[r0][h] = m0 * tau_s[r0];
    ms[r1][h] = m1 * tau_s[r1];
  }
  __syncthreads();

  // ---- y = relu(Wa . m + ba) + Wr . x + br ----
  {
    const int h = t & 127;
    const int g4 = t >> 7;
    const int r0 = 2 * g4, r1 = 2 * g4 + 1;
    float q0 = ba[h], q1 = q0, c0 = br[h], c1 = c0;
    const float4* wa = (const float4*)(Wa + (size_t)h * Dn);
    const float4* wr = (const float4*)(Wr + (size_t)h * Dn);
#pragma unroll 4
    for (int k4 = 0; k4 < Dn / 4; ++k4) {
      const float4 av = wa[k4];
      const float4 rv = wr[k4];
      const int k = k4 * 4;
      q0 += av.x * ms[r0][k] + av.y * ms[r0][k + 1] + av.z * ms[r0][k + 2] +
            av.w * ms[r0][k + 3];
      q1 += av.x * ms[r1][k] + av.y * ms[r1][k + 1] + av.z * ms[r1][k + 2] +
            av.w * ms[r1][k + 3];
      c0 += rv.x * xs[r0][k] + rv.y * xs[r0][k + 1] + rv.z * xs[r0][k + 2] +
            rv.w * xs[r0][k + 3];
      c1 += rv.x * xs[r1][k] + rv.y * xs[r1][k + 1] + rv.z * xs[r1][k + 2] +
            rv.w * xs[r1][k + 3];
    }
    ys[r0][h] = fmaxf(q0, 0.f) + c0;
    ys[r1][h] = fmaxf(q1, 0.f) + c1;
  }
  __syncthreads();

  // ---- LayerNorm (one wave per row) ----
  {
    const int r = t >> 6, p = t & 63;
    const float v0 = ys[r][p], v1 = ys[r][p + 64];
    float s = v0 + v1;
    float q = v0 * v0 + v1 * v1;
#pragma unroll
    for (int off = 32; off; off >>= 1) {
      s += __shfl_xor(s, off, 64);
      q += __shfl_xor(q, off, 64);
    }
    const float mu = s * (1.0f / 128.0f);
    const float var = q * (1.0f / 128.0f) - mu * mu;
    const float rs = rsqrtf(var + 1e-5f);
    float* o = out + (size_t)(i0 + r) * Hn;
    o[p] = (v0 - mu) * rs * gamma[p] + beta[p];
    o[p + 64] = (v1 - mu) * rs * gamma[p + 64] + beta[p + 64];
  }
}

extern "C" void kernel_launch(void* const* d_in, const int* in_sizes, int n_in,
                              void* d_out, int out_size, void* d_ws,
                              size_t ws_size, hipStream_t stream) {
  const float* x = (const float*)d_in[0];
  const float* Wd = (const float*)d_in[1];
  const float* bd = (const float*)d_in[2];
  const float* Wt = (const float*)d_in[3];
  const float* bt = (const float*)d_in[4];
  const float* Wa = (const float*)d_in[5];
  const float* ba = (const float*)d_in[6];
  const float* Wr = (const float*)d_in[7];
  const float* br = (const float*)d_in[8];
  const float* gamma = (const float*)d_in[9];
  const float* beta = (const float*)d_in[10];
  float* out = (float*)d_out;
  float* dmean = (float*)d_ws;  // B*D*4 = 512 KB scratch

  col_sort_dmean<<<Dn, Bn, 0, stream>>>(x, dmean);
  fused_tail<<<Bn / 4, 256, 0, stream>>>(x, dmean, Wd, bd, Wt, bt, Wa, ba, Wr,
                                         br, gamma, beta, out);
  (void)in_sizes; (void)n_in; (void)out_size; (void)ws_size;
}